// Round 1
// baseline (107.854 us; speedup 1.0000x reference)
//
#include <hip/hip_runtime.h>
#include <math.h>

#define NPOS 1024   // H*W
#define DH   32     // dim head
#define NBH  8      // B * HEADS
#define CH   256
#define INNER 128   // HEADS*DIM_HEAD

// ---------------------------------------------------------------------------
// Kernel A: QKV projections.  out_p[b, i, n] = sum_c W_p[i,c] * x[b,c,n]
// Stored as [bh][n][d] (row-major per spatial position).
// WG = 256 threads: lane = n-offset (64), it = i-subgroup (4), 4 i per thread.
// ---------------------------------------------------------------------------
__global__ __launch_bounds__(256) void proj_kernel(
    const float* __restrict__ x, const float* __restrict__ Wq,
    const float* __restrict__ Wk, const float* __restrict__ Wv,
    float* __restrict__ Q, float* __restrict__ K, float* __restrict__ V)
{
  const int lane  = threadIdx.x & 63;
  const int it    = threadIdx.x >> 6;       // 0..3
  const int ntile = blockIdx.x;             // 0..15
  const int ig    = blockIdx.y;             // 0..7
  const int pz    = blockIdx.z;             // 0..5  (p*2 + b)
  const int p = pz >> 1;
  const int b = pz & 1;
  const int n  = ntile * 64 + lane;
  const int i0 = ig * 16 + it * 4;

  const float* W   = (p == 0) ? Wq : ((p == 1) ? Wk : Wv);
  float*       Out = (p == 0) ? Q  : ((p == 1) ? K  : V);

  const float* xb = x + (size_t)b * CH * NPOS + n;
  const float* w0 = W + (size_t)i0 * CH;

  float acc0 = 0.f, acc1 = 0.f, acc2 = 0.f, acc3 = 0.f;
  #pragma unroll 4
  for (int c = 0; c < CH; ++c) {
    float xv = xb[(size_t)c * NPOS];
    acc0 += w0[c]          * xv;
    acc1 += w0[CH + c]     * xv;
    acc2 += w0[2 * CH + c] * xv;
    acc3 += w0[3 * CH + c] * xv;
  }
  #pragma unroll
  for (int j = 0; j < 4; ++j) {
    int i = i0 + j;
    float a = (j == 0) ? acc0 : ((j == 1) ? acc1 : ((j == 2) ? acc2 : acc3));
    // layout: [(b*4 + h)][n][d]
    Out[(size_t)(b * 4 + (i >> 5)) * (NPOS * DH) + (size_t)n * DH + (i & 31)] = a;
  }
}

// ---------------------------------------------------------------------------
// Kernel B: fused scores -> KAN -> fixed-bound exp -> PV, split over m.
// Thread = query row (lane=row).  k/v rows are wave-uniform loads.
// Writes partial O ([sp][bh][d][n], coalesced) and partial S.
// ---------------------------------------------------------------------------
__global__ __launch_bounds__(256, 2) void attn_partial(
    const float* __restrict__ Q, const float* __restrict__ K,
    const float* __restrict__ V,
    const float* __restrict__ bwp, const float* __restrict__ swp,
    const float* __restrict__ ssp,
    float* __restrict__ Opart, float* __restrict__ Spart, int mblk)
{
  __shared__ float coefL[8];
  const int tid = threadIdx.x;
  const int bh  = blockIdx.x;   // 0..7
  const int rt  = blockIdx.y;   // 0..3
  const int sp  = blockIdx.z;   // 0..splits-1

  if (tid < 8) coefL[tid] = swp[tid] * ssp[0];
  __syncthreads();

  const int row = rt * 256 + tid;   // 0..1023
  const float* q = Q + ((size_t)bh * NPOS + row) * DH;

  float qr[32];
  #pragma unroll
  for (int j = 0; j < 8; ++j) {
    float4 t = ((const float4*)q)[j];
    qr[4 * j + 0] = t.x; qr[4 * j + 1] = t.y;
    qr[4 * j + 2] = t.z; qr[4 * j + 3] = t.w;
  }

  const float base_w = bwp[0];
  float maxc = 0.f;
  #pragma unroll
  for (int k2 = 0; k2 < 8; ++k2) maxc = fmaxf(maxc, fabsf(coefL[k2]));
  const float Bnd = fabsf(base_w) * 6.0f + maxc;   // >= max over x of kan(x)

  float O[32];
  #pragma unroll
  for (int j = 0; j < 32; ++j) O[j] = 0.f;
  float Ssum = 0.f;

  const float* kb = K + ((size_t)bh * NPOS + (size_t)sp * mblk) * DH;
  const float* vb = V + ((size_t)bh * NPOS + (size_t)sp * mblk) * DH;

  for (int mm = 0; mm < mblk; ++mm) {
    // ---- score: dot(q_row, k_row) ----
    const float4* kr = (const float4*)(kb + (size_t)mm * DH);
    float s0 = 0.f, s1 = 0.f, s2 = 0.f, s3 = 0.f;
    #pragma unroll
    for (int j = 0; j < 8; ++j) {
      float4 kv = kr[j];
      s0 += qr[4 * j + 0] * kv.x;
      s1 += qr[4 * j + 1] * kv.y;
      s2 += qr[4 * j + 2] * kv.z;
      s3 += qr[4 * j + 3] * kv.w;
    }
    float s = ((s0 + s1) + (s2 + s3)) * 0.17677669529663687f; // 1/sqrt(32)

    // ---- _safe: clip to [-6,6] (inputs finite -> no NaN path needed) ----
    s = fminf(fmaxf(s, -6.0f), 6.0f);

    // ---- KAN: base_w * silu(s) + uniform cubic B-spline ----
    float e   = __expf(-s);
    float sil = s * __builtin_amdgcn_rcpf(1.0f + e);

    float t  = (s + 6.0f) * (1.0f / 2.4f);   // in [0,5]
    float cf = floorf(t);
    cf = fminf(cf, 4.0f);
    int   ci = (int)cf;
    float u  = t - cf;                        // in [0,1]
    float u2 = u * u, u3 = u2 * u;
    float om = 1.0f - u;
    float w0 = om * om * om * (1.0f / 6.0f);
    float w1 = (3.0f * u3 - 6.0f * u2 + 4.0f) * (1.0f / 6.0f);
    float w2 = (-3.0f * u3 + 3.0f * u2 + 3.0f * u + 1.0f) * (1.0f / 6.0f);
    float w3 = u3 * (1.0f / 6.0f);
    float spl = w0 * coefL[ci] + w1 * coefL[ci + 1] +
                w2 * coefL[ci + 2] + w3 * coefL[ci + 3];
    float kan = base_w * sil + spl;

    // ---- fixed-bound softmax numerator ----
    float pr = __expf(kan - Bnd);
    Ssum += pr;

    // ---- PV accumulate ----
    const float4* vr = (const float4*)(vb + (size_t)mm * DH);
    #pragma unroll
    for (int j = 0; j < 8; ++j) {
      float4 vv = vr[j];
      O[4 * j + 0] += pr * vv.x;
      O[4 * j + 1] += pr * vv.y;
      O[4 * j + 2] += pr * vv.z;
      O[4 * j + 3] += pr * vv.w;
    }
  }

  // write partials: Opart [sp][bh][d][n]  (lanes = consecutive n -> coalesced)
  float* ob = Opart + ((size_t)(sp * NBH + bh) * DH) * NPOS;
  #pragma unroll
  for (int d = 0; d < 32; ++d) ob[(size_t)d * NPOS + row] = O[d];
  Spart[(size_t)(sp * NBH + bh) * NPOS + row] = Ssum;
}

// ---------------------------------------------------------------------------
// Kernel C: reduce over splits + normalize.  Onorm [bh][d][n] == [b][i][n].
// ---------------------------------------------------------------------------
__global__ __launch_bounds__(256) void reduce_kernel(
    const float* __restrict__ Opart, const float* __restrict__ Spart,
    float* __restrict__ Onorm, int splits)
{
  int gid = blockIdx.x * 256 + threadIdx.x;   // 0..262143
  int n  = gid & (NPOS - 1);
  int d  = (gid >> 10) & 31;
  int bh = gid >> 15;
  float o = 0.f, ssum = 0.f;
  for (int sp = 0; sp < splits; ++sp) {
    o    += Opart[((size_t)(sp * NBH + bh) * DH + d) * NPOS + n];
    ssum += Spart[(size_t)(sp * NBH + bh) * NPOS + n];
  }
  Onorm[((size_t)bh * DH + d) * NPOS + n] = o / ssum;
}

// ---------------------------------------------------------------------------
// Kernel D: output projection. out[b,c,n] = sum_i Wo[c,i] * Onorm[b*128+i][n]
// ---------------------------------------------------------------------------
__global__ __launch_bounds__(256) void outproj_kernel(
    const float* __restrict__ Onorm, const float* __restrict__ Wo,
    float* __restrict__ out)
{
  const int lane  = threadIdx.x & 63;
  const int it    = threadIdx.x >> 6;
  const int ntile = blockIdx.x;   // 0..15
  const int cg    = blockIdx.y;   // 0..15
  const int b     = blockIdx.z;   // 0..1
  const int n  = ntile * 64 + lane;
  const int c0 = cg * 16 + it * 4;

  const float* ob = Onorm + (size_t)b * INNER * NPOS + n;
  const float* w0 = Wo + (size_t)c0 * INNER;

  float acc0 = 0.f, acc1 = 0.f, acc2 = 0.f, acc3 = 0.f;
  #pragma unroll 4
  for (int i = 0; i < INNER; ++i) {
    float xv = ob[(size_t)i * NPOS];
    acc0 += w0[i]             * xv;
    acc1 += w0[INNER + i]     * xv;
    acc2 += w0[2 * INNER + i] * xv;
    acc3 += w0[3 * INNER + i] * xv;
  }
  out[((size_t)(b * CH + c0 + 0)) * NPOS + n] = acc0;
  out[((size_t)(b * CH + c0 + 1)) * NPOS + n] = acc1;
  out[((size_t)(b * CH + c0 + 2)) * NPOS + n] = acc2;
  out[((size_t)(b * CH + c0 + 3)) * NPOS + n] = acc3;
}

// ---------------------------------------------------------------------------
extern "C" void kernel_launch(void* const* d_in, const int* in_sizes, int n_in,
                              void* d_out, int out_size, void* d_ws, size_t ws_size,
                              hipStream_t stream)
{
  const float* x  = (const float*)d_in[0];
  const float* Wq = (const float*)d_in[1];
  const float* Wk = (const float*)d_in[2];
  const float* Wv = (const float*)d_in[3];
  const float* Wo = (const float*)d_in[4];
  const float* bw = (const float*)d_in[5];
  const float* sw = (const float*)d_in[6];
  const float* ss = (const float*)d_in[7];
  float* out = (float*)d_out;
  float* ws  = (float*)d_ws;

  // pick splits that fit the workspace
  int splits = 16;
  while (splits > 1) {
    size_t need = ((size_t)3 * NBH * NPOS * DH          // Q,K,V
                 + (size_t)splits * NBH * DH * NPOS     // Opart
                 + (size_t)splits * NBH * NPOS          // Spart
                 + (size_t)NBH * DH * NPOS)             // Onorm
                 * sizeof(float);
    if (need <= ws_size) break;
    splits >>= 1;
  }

  float* Q     = ws;
  float* K     = Q + (size_t)NBH * NPOS * DH;
  float* V     = K + (size_t)NBH * NPOS * DH;
  float* Opart = V + (size_t)NBH * NPOS * DH;
  float* Spart = Opart + (size_t)splits * NBH * DH * NPOS;
  float* Onorm = Spart + (size_t)splits * NBH * NPOS;

  proj_kernel<<<dim3(16, 8, 6), 256, 0, stream>>>(x, Wq, Wk, Wv, Q, K, V);
  attn_partial<<<dim3(8, 4, splits), 256, 0, stream>>>(
      Q, K, V, bw, sw, ss, Opart, Spart, NPOS / splits);
  reduce_kernel<<<dim3((NBH * DH * NPOS) / 256), 256, 0, stream>>>(
      Opart, Spart, Onorm, splits);
  outproj_kernel<<<dim3(16, 16, 2), 256, 0, stream>>>(Onorm, Wo, out);
}